// Round 1
// baseline (235.746 us; speedup 1.0000x reference)
//
#include <hip/hip_runtime.h>

// YOLO loss: S=1024, B=2, NPRED=5, C=20 -> 30 channels per cell.
// pred/target: [S, S, 30] float32, channel-last contiguous.
// loss = 5*xy + 5*box + conf + noobj + cls  (conf+noobj = (conf_t-conf_p)^2)

constexpr int S_DIM  = 1024;
constexpr int NCELL  = S_DIM * S_DIM;     // 1,048,576
constexpr int NPAIR  = NCELL / 2;         // 524,288 cell-pairs (240B each, 16B aligned)
constexpr int BLOCK  = 256;
constexpr int GRID   = NPAIR / BLOCK;     // 2048 blocks, exactly 1 pair/thread

__device__ __forceinline__ float wave_reduce_sum(float v) {
#pragma unroll
    for (int off = 32; off > 0; off >>= 1)
        v += __shfl_down(v, off, 64);
    return v;
}

__global__ __launch_bounds__(BLOCK) void yolo_partial_kernel(
        const float* __restrict__ pred,
        const float* __restrict__ tgt,
        float* __restrict__ partial) {
    const int tid = blockIdx.x * BLOCK + threadIdx.x;

    float acc = 0.0f;

    for (int pair = tid; pair < NPAIR; pair += GRID * BLOCK) {
        // Load 60 floats (2 cells) from each tensor as 15 float4s (16B aligned).
        float p[60], t[60];
        const float4* p4 = reinterpret_cast<const float4*>(pred + (size_t)pair * 60);
        const float4* t4 = reinterpret_cast<const float4*>(tgt  + (size_t)pair * 60);
#pragma unroll
        for (int k = 0; k < 15; ++k)
            *reinterpret_cast<float4*>(&p[4 * k]) = p4[k];
#pragma unroll
        for (int k = 0; k < 15; ++k)
            *reinterpret_cast<float4*>(&t[4 * k]) = t4[k];

#pragma unroll
        for (int c = 0; c < 2; ++c) {
            const float* pp = p + 30 * c;
            const float* tt = t + 30 * c;

            // Two boxes: channels [5b .. 5b+4] = (conf, x, y, w, h)
#pragma unroll
            for (int b = 0; b < 2; ++b) {
                const float* bp = pp + 5 * b;
                const float* bt = tt + 5 * b;
                const float conf_p = bp[0];
                const float x_p = bp[1], y_p = bp[2];
                const float w_p = sqrtf(fabsf(bp[3]));
                const float h_p = sqrtf(fabsf(bp[4]));
                const float conf_t = bt[0];
                const float x_t = bt[1], y_t = bt[2];
                const float w_t = sqrtf(bt[3]);
                const float h_t = sqrtf(bt[4]);

                const float dx = x_t - x_p, dy = y_t - y_p;
                const float dw = w_t - w_p, dh = h_t - h_p;
                const float dc = conf_t - conf_p;
                const float csq = dc * dc;

                // 5*xy_loss + 5*box_loss + csq*conf_t + csq*(1-conf_t)
                acc += 5.0f * ((dx * dx + dy * dy) * conf_t)
                     + 5.0f * ((dw * dw + dh * dh) * conf_t)
                     + csq;
            }

            // Class term: channels 10..29. mask = (sum(tgt_cls) == 1.0)
            float ssum = 0.0f, per_cell = 0.0f;
#pragma unroll
            for (int k = 0; k < 20; ++k) {
                const float tc = tt[10 + k];
                const float pc = pp[10 + k];
                ssum     += tc;
                per_cell += tc * tc - pc * pc;
            }
            const float mask = (ssum == 1.0f) ? 1.0f : 0.0f;
            acc += per_cell * mask;
        }
    }

    // Block reduction: wave(64) shuffle -> LDS across 4 waves.
    __shared__ float lds[BLOCK / 64];
    const int lane = threadIdx.x & 63;
    const int wid  = threadIdx.x >> 6;

    float v = wave_reduce_sum(acc);
    if (lane == 0) lds[wid] = v;
    __syncthreads();
    if (wid == 0) {
        v = (lane < (BLOCK / 64)) ? lds[lane] : 0.0f;
        v = wave_reduce_sum(v);
        if (lane == 0) partial[blockIdx.x] = v;
    }
}

__global__ __launch_bounds__(256) void yolo_final_kernel(
        const float* __restrict__ partial,
        float* __restrict__ out,
        int n) {
    float acc = 0.0f;
    for (int i = threadIdx.x; i < n; i += 256)
        acc += partial[i];

    __shared__ float lds[4];
    const int lane = threadIdx.x & 63;
    const int wid  = threadIdx.x >> 6;
    float v = wave_reduce_sum(acc);
    if (lane == 0) lds[wid] = v;
    __syncthreads();
    if (wid == 0) {
        v = (lane < 4) ? lds[lane] : 0.0f;
        v = wave_reduce_sum(v);
        if (lane == 0) out[0] = v;
    }
}

extern "C" void kernel_launch(void* const* d_in, const int* in_sizes, int n_in,
                              void* d_out, int out_size, void* d_ws, size_t ws_size,
                              hipStream_t stream) {
    const float* pred = (const float*)d_in[0];
    const float* tgt  = (const float*)d_in[1];
    float* out        = (float*)d_out;
    float* partial    = (float*)d_ws;   // GRID floats = 8 KB

    yolo_partial_kernel<<<GRID, BLOCK, 0, stream>>>(pred, tgt, partial);
    yolo_final_kernel<<<1, 256, 0, stream>>>(partial, out, GRID);
}

// Round 2
// 46.828 us; speedup vs baseline: 5.0343x; 5.0343x over previous
//
#include <hip/hip_runtime.h>

// YOLO loss: S=1024, 30 f32 channels/cell, channel-last contiguous.
// loss = 5*xy + 5*box + (conf_t-conf_p)^2 + cls_masked
//
// Key fix vs round 0: coalesced tile staging through LDS. Round 0 gave each
// thread a contiguous 240B chunk -> strided per-instruction pattern -> 3.25x
// HBM over-fetch (FETCH 818MB vs 252MB ideal). Now each block stages a
// 256-cell tile (30KB + 30KB LDS) with lane-contiguous float4 loads, then
// computes from LDS.

constexpr int S_DIM       = 1024;
constexpr int NCELL       = S_DIM * S_DIM;       // 1,048,576
constexpr int CH          = 30;
constexpr int BLOCK       = 256;
constexpr int TILE_CELLS  = 256;                 // 1 cell / thread / tile
constexpr int TILE_FLOATS = TILE_CELLS * CH;     // 7680
constexpr int TILE_F4     = TILE_FLOATS / 4;     // 1920
constexpr int NTILES      = NCELL / TILE_CELLS;  // 4096
constexpr int GRID        = 2048;                // 2 tiles / block

__device__ __forceinline__ float wave_reduce_sum(float v) {
#pragma unroll
    for (int off = 32; off > 0; off >>= 1)
        v += __shfl_down(v, off, 64);
    return v;
}

__global__ __launch_bounds__(BLOCK, 2) void yolo_partial_kernel(
        const float* __restrict__ pred,
        const float* __restrict__ tgt,
        float* __restrict__ partial) {
    // 60KB LDS total -> 2 blocks/CU (160KB limit), phases of the two blocks
    // interleave so memory stays busy during compute.
    __shared__ float sp[TILE_FLOATS];
    __shared__ float st[TILE_FLOATS];

    const int tid = threadIdx.x;
    float acc = 0.0f;

    for (int tile = blockIdx.x; tile < NTILES; tile += GRID) {
        const float4* gp = reinterpret_cast<const float4*>(pred) + (size_t)tile * TILE_F4;
        const float4* gt = reinterpret_cast<const float4*>(tgt)  + (size_t)tile * TILE_F4;
        float4* s4p = reinterpret_cast<float4*>(sp);
        float4* s4t = reinterpret_cast<float4*>(st);

        __syncthreads();  // previous tile's compute must finish before overwrite
#pragma unroll
        for (int j = 0; j < 7; ++j) {
            const int idx = j * BLOCK + tid;  // lane-contiguous: fully coalesced
            s4p[idx] = gp[idx];
            s4t[idx] = gt[idx];
        }
        {
            const int idx = 7 * BLOCK + tid;  // 1920 = 7.5*256: half-warp tail
            if (idx < TILE_F4) { s4p[idx] = gp[idx]; s4t[idx] = gt[idx]; }
        }
        __syncthreads();

        const float* pp = sp + tid * CH;
        const float* tt = st + tid * CH;

        // Two boxes: channels [5b .. 5b+4] = (conf, x, y, w, h)
#pragma unroll
        for (int b = 0; b < 2; ++b) {
            const float conf_p = pp[5 * b + 0];
            const float x_p    = pp[5 * b + 1];
            const float y_p    = pp[5 * b + 2];
            const float w_p    = sqrtf(fabsf(pp[5 * b + 3]));
            const float h_p    = sqrtf(fabsf(pp[5 * b + 4]));
            const float conf_t = tt[5 * b + 0];
            const float x_t    = tt[5 * b + 1];
            const float y_t    = tt[5 * b + 2];
            const float w_t    = sqrtf(tt[5 * b + 3]);
            const float h_t    = sqrtf(tt[5 * b + 4]);

            const float dx = x_t - x_p, dy = y_t - y_p;
            const float dw = w_t - w_p, dh = h_t - h_p;
            const float dc = conf_t - conf_p;

            // 5*xy + 5*wh + csq*conf_t + csq*(1-conf_t) = 5*(...)*conf_t + csq
            acc += 5.0f * ((dx * dx + dy * dy) * conf_t)
                 + 5.0f * ((dw * dw + dh * dh) * conf_t)
                 + dc * dc;
        }

        // Class term: channels 10..29; mask = (sum(tgt_cls) == 1.0)
        float ssum = 0.0f, per_cell = 0.0f;
#pragma unroll
        for (int k = 0; k < 20; ++k) {
            const float tc = tt[10 + k];
            const float pc = pp[10 + k];
            ssum     += tc;
            per_cell += tc * tc - pc * pc;
        }
        acc += (ssum == 1.0f) ? per_cell : 0.0f;
    }

    // Block reduction: wave(64) shuffle -> LDS across 4 waves.
    __shared__ float red[BLOCK / 64];
    const int lane = tid & 63;
    const int wid  = tid >> 6;

    float v = wave_reduce_sum(acc);
    if (lane == 0) red[wid] = v;
    __syncthreads();
    if (wid == 0) {
        v = (lane < (BLOCK / 64)) ? red[lane] : 0.0f;
        v = wave_reduce_sum(v);
        if (lane == 0) partial[blockIdx.x] = v;
    }
}

__global__ __launch_bounds__(256) void yolo_final_kernel(
        const float* __restrict__ partial,
        float* __restrict__ out,
        int n) {
    float acc = 0.0f;
    for (int i = threadIdx.x; i < n; i += 256)
        acc += partial[i];

    __shared__ float red[4];
    const int lane = threadIdx.x & 63;
    const int wid  = threadIdx.x >> 6;
    float v = wave_reduce_sum(acc);
    if (lane == 0) red[wid] = v;
    __syncthreads();
    if (wid == 0) {
        v = (lane < 4) ? red[lane] : 0.0f;
        v = wave_reduce_sum(v);
        if (lane == 0) out[0] = v;
    }
}

extern "C" void kernel_launch(void* const* d_in, const int* in_sizes, int n_in,
                              void* d_out, int out_size, void* d_ws, size_t ws_size,
                              hipStream_t stream) {
    const float* pred = (const float*)d_in[0];
    const float* tgt  = (const float*)d_in[1];
    float* out        = (float*)d_out;
    float* partial    = (float*)d_ws;   // GRID floats = 8 KB

    yolo_partial_kernel<<<GRID, BLOCK, 0, stream>>>(pred, tgt, partial);
    yolo_final_kernel<<<1, 256, 0, stream>>>(partial, out, GRID);
}

// Round 3
// 45.209 us; speedup vs baseline: 5.2145x; 1.0358x over previous
//
#include <hip/hip_runtime.h>

// YOLO loss: S=1024, 30 f32 channels/cell, channel-last contiguous.
// loss = 5*xy + 5*box + (conf_t-conf_p)^2 + cls_masked
//
// R1: coalesced LDS staging fixed 3.25x over-fetch (236 -> 46.8us).
// R2 theory: 60KB LDS capped us at 2 blocks/CU (occupancy 19.5%) -> latency
// bound. Now: 128-cell tiles (30KB LDS) -> 5 blocks/CU, and half-a-cell per
// thread in the compute phase (one box + 10 class channels each, class mask
// combined across the thread pair with one shfl_xor).

constexpr int S_DIM       = 1024;
constexpr int NCELL       = S_DIM * S_DIM;       // 1,048,576
constexpr int CH          = 30;
constexpr int BLOCK       = 256;
constexpr int TILE_CELLS  = 128;                 // half-cell per thread
constexpr int TILE_FLOATS = TILE_CELLS * CH;     // 3840 floats = 15KB
constexpr int TILE_F4     = TILE_FLOATS / 4;     // 960
constexpr int NTILES      = NCELL / TILE_CELLS;  // 8192
constexpr int GRID        = 2048;                // 4 tiles / block

__device__ __forceinline__ float wave_reduce_sum(float v) {
#pragma unroll
    for (int off = 32; off > 0; off >>= 1)
        v += __shfl_down(v, off, 64);
    return v;
}

__global__ __launch_bounds__(BLOCK, 5) void yolo_partial_kernel(
        const float* __restrict__ pred,
        const float* __restrict__ tgt,
        float* __restrict__ partial) {
    // 30KB LDS -> 5 blocks/CU (150KB of 160KB), 20 waves/CU.
    __shared__ float sp[TILE_FLOATS];
    __shared__ float st[TILE_FLOATS];

    const int tid  = threadIdx.x;
    const int cell = tid >> 1;        // 0..127
    const int half = tid & 1;         // which box / class half
    float acc = 0.0f;

    for (int tile = blockIdx.x; tile < NTILES; tile += GRID) {
        const float4* gp = reinterpret_cast<const float4*>(pred) + (size_t)tile * TILE_F4;
        const float4* gt = reinterpret_cast<const float4*>(tgt)  + (size_t)tile * TILE_F4;
        float4* s4p = reinterpret_cast<float4*>(sp);
        float4* s4t = reinterpret_cast<float4*>(st);

        __syncthreads();  // previous tile's compute must finish before overwrite
#pragma unroll
        for (int j = 0; j < 3; ++j) {
            const int idx = j * BLOCK + tid;  // lane-contiguous: fully coalesced
            s4p[idx] = gp[idx];
            s4t[idx] = gt[idx];
        }
        {
            const int idx = 3 * BLOCK + tid;  // 960 = 3.75*256 tail (3 of 4 waves)
            if (idx < TILE_F4) { s4p[idx] = gp[idx]; s4t[idx] = gt[idx]; }
        }
        __syncthreads();

        const float* pp = sp + cell * CH;
        const float* tt = st + cell * CH;

        // This thread's box: channels [5*half .. 5*half+4] = (conf, x, y, w, h)
        {
            const int o = 5 * half;
            const float conf_p = pp[o + 0];
            const float x_p    = pp[o + 1];
            const float y_p    = pp[o + 2];
            const float w_p    = sqrtf(fabsf(pp[o + 3]));
            const float h_p    = sqrtf(fabsf(pp[o + 4]));
            const float conf_t = tt[o + 0];
            const float x_t    = tt[o + 1];
            const float y_t    = tt[o + 2];
            const float w_t    = sqrtf(tt[o + 3]);
            const float h_t    = sqrtf(tt[o + 4]);

            const float dx = x_t - x_p, dy = y_t - y_p;
            const float dw = w_t - w_p, dh = h_t - h_p;
            const float dc = conf_t - conf_p;

            acc += 5.0f * ((dx * dx + dy * dy) * conf_t)
                 + 5.0f * ((dw * dw + dh * dh) * conf_t)
                 + dc * dc;
        }

        // This thread's class half: channels [10+10*half .. 10+10*half+9].
        // mask = (sum over ALL 20 target class channels == 1.0) -> combine
        // the two halves' sums across the adjacent-lane pair.
        float ssum = 0.0f, per_cell = 0.0f;
        const int co = 10 + 10 * half;
#pragma unroll
        for (int k = 0; k < 10; ++k) {
            const float tc = tt[co + k];
            const float pc = pp[co + k];
            ssum     += tc;
            per_cell += tc * tc - pc * pc;
        }
        const float tot = ssum + __shfl_xor(ssum, 1, 64);
        acc += (tot == 1.0f) ? per_cell : 0.0f;  // both halves add -> full term
    }

    // Block reduction: wave(64) shuffle -> LDS across 4 waves.
    __shared__ float red[BLOCK / 64];
    const int lane = tid & 63;
    const int wid  = tid >> 6;

    float v = wave_reduce_sum(acc);
    if (lane == 0) red[wid] = v;
    __syncthreads();
    if (wid == 0) {
        v = (lane < (BLOCK / 64)) ? red[lane] : 0.0f;
        v = wave_reduce_sum(v);
        if (lane == 0) partial[blockIdx.x] = v;
    }
}

__global__ __launch_bounds__(256) void yolo_final_kernel(
        const float* __restrict__ partial,
        float* __restrict__ out,
        int n) {
    float acc = 0.0f;
    for (int i = threadIdx.x; i < n; i += 256)
        acc += partial[i];

    __shared__ float red[4];
    const int lane = threadIdx.x & 63;
    const int wid  = threadIdx.x >> 6;
    float v = wave_reduce_sum(acc);
    if (lane == 0) red[wid] = v;
    __syncthreads();
    if (wid == 0) {
        v = (lane < 4) ? red[lane] : 0.0f;
        v = wave_reduce_sum(v);
        if (lane == 0) out[0] = v;
    }
}

extern "C" void kernel_launch(void* const* d_in, const int* in_sizes, int n_in,
                              void* d_out, int out_size, void* d_ws, size_t ws_size,
                              hipStream_t stream) {
    const float* pred = (const float*)d_in[0];
    const float* tgt  = (const float*)d_in[1];
    float* out        = (float*)d_out;
    float* partial    = (float*)d_ws;   // GRID floats = 8 KB

    yolo_partial_kernel<<<GRID, BLOCK, 0, stream>>>(pred, tgt, partial);
    yolo_final_kernel<<<1, 256, 0, stream>>>(partial, out, GRID);
}